// Round 1
// baseline (201.918 us; speedup 1.0000x reference)
//
#include <hip/hip_runtime.h>
#include <math.h>

// Problem constants (must match reference)
#define NB   2        // images
#define NP   1024     // proposals per image
#define NC   61       // classes incl. background
#define NFG  60       // foreground classes
#define KTOP 100      // detections per image
#define CAP  61440    // worst-case candidates per image (NFG*NP)
#define SELCAP 2048   // top-k collection buffer

__device__ __forceinline__ float clampf(float x, float lo, float hi) {
  return fminf(fmaxf(x, lo), hi);
}

// ---------------------------------------------------------------------------
// Kernel A: per-row softmax stats (max, sum of exp) + zero candidate counters
// one wave (64 lanes) per row of 61 logits
// ---------------------------------------------------------------------------
__global__ void rowstats_kernel(const float* __restrict__ logits,
                                float* __restrict__ rowmax,
                                float* __restrict__ rowsum,
                                int* __restrict__ ccnt) {
  if (blockIdx.x == 0 && threadIdx.x < NB) ccnt[threadIdx.x] = 0;
  int wave = threadIdx.x >> 6, lane = threadIdx.x & 63;
  int row = blockIdx.x * 4 + wave;
  if (row >= NB * NP) return;
  float x = (lane < NC) ? logits[row * NC + lane] : -INFINITY;
  float m = x;
  #pragma unroll
  for (int o = 32; o; o >>= 1) m = fmaxf(m, __shfl_xor(m, o, 64));
  float e = (lane < NC) ? expf(x - m) : 0.0f;
  float s = e;
  #pragma unroll
  for (int o = 32; o; o >>= 1) s += __shfl_xor(s, o, 64);
  if (lane == 0) { rowmax[row] = m; rowsum[row] = s; }
}

// ---------------------------------------------------------------------------
// Kernel B: one block per (image, fg class): threshold-compact, decode,
// exact stable sort (score desc, index asc), greedy NMS, append candidates.
// ---------------------------------------------------------------------------
__global__ void __launch_bounds__(256)
nms_kernel(const float* __restrict__ logits,
           const float* __restrict__ deltas,
           const float* __restrict__ props,
           const float* __restrict__ rowmax,
           const float* __restrict__ rowsum,
           float* __restrict__ cscore,
           int* __restrict__ cflat,
           int* __restrict__ clabel,
           float* __restrict__ cbox,
           int* __restrict__ ccnt) {
  const float SCALE_CLAMP = 4.135166556742356f;  // float(log(1000/16))
  int b = blockIdx.x / NFG;
  int j = blockIdx.x % NFG;
  int cls = j + 1;
  int tid = threadIdx.x;

  __shared__ float sc_key[NP];   // compacted scores (unsorted)
  __shared__ int   sc_n[NP];     // compacted original proposal index
  __shared__ float so_key[NP];   // sorted scores
  __shared__ int   so_p[NP];     // sorted -> compact index
  __shared__ float bxs[NP][4];   // decoded+clipped boxes (compact order)
  __shared__ unsigned char sup[NP]; // suppression flags (sorted order)
  __shared__ int s_nv;

  if (tid == 0) s_nv = 0;
  __syncthreads();

  // 1) score + threshold compaction (valid entries only matter for NMS:
  //    invalid can neither be kept nor suppress anything)
  for (int n = tid; n < NP; n += 256) {
    int row = b * NP + n;
    float sc = expf(logits[row * NC + cls] - rowmax[row]) / rowsum[row];
    if (sc > 0.05f) {
      int p = atomicAdd(&s_nv, 1);
      sc_key[p] = sc;
      sc_n[p] = n;
    }
  }
  __syncthreads();
  int nv = s_nv;

  // 2) decode boxes only for valid entries
  for (int p = tid; p < nv; p += 256) {
    int n = sc_n[p];
    int row = b * NP + n;
    const float* pr = props + row * 4;
    float w = pr[2] - pr[0], h = pr[3] - pr[1];
    float cx = pr[0] + 0.5f * w, cy = pr[1] + 0.5f * h;
    const float* dd = deltas + (size_t)row * (NC * 4) + cls * 4;
    float dx = dd[0] / 10.0f, dy = dd[1] / 10.0f;
    float dw = fminf(dd[2] / 5.0f, SCALE_CLAMP);
    float dh = fminf(dd[3] / 5.0f, SCALE_CLAMP);
    float pcx = dx * w + cx, pcy = dy * h + cy;
    float pw = expf(dw) * w, ph = expf(dh) * h;
    bxs[p][0] = clampf(pcx - 0.5f * pw, 0.0f, 1024.0f);
    bxs[p][1] = clampf(pcy - 0.5f * ph, 0.0f, 1024.0f);
    bxs[p][2] = clampf(pcx + 0.5f * pw, 0.0f, 1024.0f);
    bxs[p][3] = clampf(pcy + 0.5f * ph, 0.0f, 1024.0f);
    sup[p] = 0;
  }
  __syncthreads();

  // 3) exact rank sort: (score desc, original index asc) — matches stable
  //    argsort(-key_s). Strict total order (indices unique) => ranks unique.
  for (int e = tid; e < nv; e += 256) {
    float ke = sc_key[e]; int ne = sc_n[e];
    int r = 0;
    for (int m = 0; m < nv; ++m) {
      float km = sc_key[m]; int nm = sc_n[m];
      if (km > ke || (km == ke && nm < ne)) ++r;
    }
    so_key[r] = ke;
    so_p[r] = e;
  }
  __syncthreads();

  // 4) greedy NMS over sorted valid entries (sequential chain length nv)
  for (int i = 0; i < nv; ++i) {
    bool kept = (sup[i] == 0);       // uniform read across block
    __syncthreads();                 // reads done before any writes below
    if (kept) {
      int pi = so_p[i];
      float ax1 = bxs[pi][0], ay1 = bxs[pi][1];
      float ax2 = bxs[pi][2], ay2 = bxs[pi][3];
      float ai = (ax2 - ax1) * (ay2 - ay1);
      for (int t = tid; t < nv; t += 256) {
        int pt = so_p[t];
        float b1 = bxs[pt][0], b2 = bxs[pt][1];
        float b3 = bxs[pt][2], b4 = bxs[pt][3];
        float at = (b3 - b1) * (b4 - b2);
        float iw = fmaxf(fminf(ax2, b3) - fmaxf(ax1, b1), 0.0f);
        float ih = fmaxf(fminf(ay2, b4) - fmaxf(ay1, b2), 0.0f);
        float inter = iw * ih;
        float iou = inter / (ai + at - inter + 1e-9f);
        if (iou > 0.5f) sup[t] = 1;
      }
      if (tid == 0) {
        int slot = atomicAdd(&ccnt[b], 1);
        if (slot < CAP) {
          int base = b * CAP + slot;
          cscore[base] = so_key[i];
          cflat[base]  = j * NP + i;   // flat index in reference layout
          clabel[base] = cls;
          cbox[base * 4 + 0] = ax1;
          cbox[base * 4 + 1] = ay1;
          cbox[base * 4 + 2] = ax2;
          cbox[base * 4 + 3] = ay2;
        }
      }
    }
    __syncthreads();                 // sup updates visible for next i
  }
}

// ---------------------------------------------------------------------------
// Kernel C: per-image exact top-100 (score desc, flat-index asc tie-break),
// via histogram threshold + exact rank sort of the surviving ~O(100) set.
// Pads with (box=0, score=0, label=1) if fewer than 100 candidates — which is
// exactly what the reference's top_k over the zero-filled flat array yields.
// ---------------------------------------------------------------------------
__global__ void __launch_bounds__(256)
topk_kernel(const float* __restrict__ cscore,
            const int* __restrict__ cflat,
            const int* __restrict__ clabel,
            const float* __restrict__ cbox,
            const int* __restrict__ ccnt,
            float* __restrict__ out) {
  int b = blockIdx.x;
  int tid = threadIdx.x;
  int cnt = ccnt[b]; if (cnt > CAP) cnt = CAP;
  const float* cs = cscore + b * CAP;
  const int* cf = cflat + b * CAP;

  __shared__ int hist[256];
  __shared__ int s_thr, s_sel;
  __shared__ float sel_s[SELCAP];
  __shared__ int sel_f[SELCAP];
  __shared__ int sel_i[SELCAP];
  __shared__ int order[KTOP];

  for (int i = tid; i < 256; i += 256) hist[i] = 0;
  __syncthreads();
  for (int i = tid; i < cnt; i += 256) {
    float s = cs[i];
    int bin = (int)(s * 256.0f);
    bin = bin < 0 ? 0 : (bin > 255 ? 255 : bin);
    atomicAdd(&hist[bin], 1);
  }
  __syncthreads();
  if (tid == 0) {
    int acc = 0, t = 255;
    for (; t >= 0; --t) { acc += hist[t]; if (acc >= KTOP) break; }
    s_thr = (acc >= KTOP) ? t : 0;
    s_sel = 0;
  }
  __syncthreads();
  int thr = s_thr;
  for (int i = tid; i < cnt; i += 256) {
    float s = cs[i];
    int bin = (int)(s * 256.0f);
    bin = bin < 0 ? 0 : (bin > 255 ? 255 : bin);
    if (bin >= thr) {
      int p = atomicAdd(&s_sel, 1);
      if (p < SELCAP) { sel_s[p] = s; sel_f[p] = cf[i]; sel_i[p] = i; }
    }
  }
  __syncthreads();
  int nsel = s_sel < SELCAP ? s_sel : SELCAP;

  // exact rank sort of selected set: (score desc, flat idx asc)
  for (int e = tid; e < nsel; e += 256) {
    float ke = sel_s[e]; int fe = sel_f[e];
    int r = 0;
    for (int m = 0; m < nsel; ++m) {
      float km = sel_s[m]; int fm = sel_f[m];
      if (km > ke || (km == ke && fm < fe)) ++r;
    }
    if (r < KTOP) order[r] = e;
  }
  __syncthreads();

  for (int k = tid; k < KTOP; k += 256) {
    float* det = out + (size_t)(b * KTOP + k) * 5;
    float lab;
    if (k < nsel) {
      int e = order[k];
      int ci = sel_i[e];
      const float* bxp = cbox + (size_t)(b * CAP + ci) * 4;
      det[0] = bxp[0]; det[1] = bxp[1]; det[2] = bxp[2]; det[3] = bxp[3];
      det[4] = sel_s[e];
      lab = (float)clabel[b * CAP + ci];
    } else {
      det[0] = det[1] = det[2] = det[3] = 0.0f;
      det[4] = 0.0f;
      lab = 1.0f;  // zero-ties in top_k resolve to class-0 flat slots => label 1
    }
    out[NB * KTOP * 5 + b * KTOP + k] = lab;
  }
}

// ---------------------------------------------------------------------------
extern "C" void kernel_launch(void* const* d_in, const int* in_sizes, int n_in,
                              void* d_out, int out_size, void* d_ws, size_t ws_size,
                              hipStream_t stream) {
  (void)in_sizes; (void)n_in; (void)out_size; (void)ws_size;
  const float* logits = (const float*)d_in[0];   // [B*N, C]
  const float* deltas = (const float*)d_in[1];   // [B*N, C*4]
  const float* props  = (const float*)d_in[2];   // [B, N, 4]
  float* out = (float*)d_out;                    // dets [B,K,5] then labels [B,K]

  // workspace layout (float elements)
  float* wf     = (float*)d_ws;
  float* rowmax = wf;                         // 2048
  float* rowsum = wf + NB * NP;               // 2048
  int*   ccnt   = (int*)(wf + 2 * NB * NP);   // 2 (+2 pad)
  float* cscore = wf + 2 * NB * NP + 4;                       // NB*CAP
  int*   cflat  = (int*)(cscore + (size_t)NB * CAP);          // NB*CAP
  int*   clabel = (int*)(cscore + 2 * (size_t)NB * CAP);      // NB*CAP
  float* cbox   = cscore + 3 * (size_t)NB * CAP;              // NB*CAP*4

  rowstats_kernel<<<(NB * NP) / 4, 256, 0, stream>>>(logits, rowmax, rowsum, ccnt);
  nms_kernel<<<NB * NFG, 256, 0, stream>>>(logits, deltas, props, rowmax, rowsum,
                                           cscore, cflat, clabel, cbox, ccnt);
  topk_kernel<<<NB, 256, 0, stream>>>(cscore, cflat, clabel, cbox, ccnt, out);
}

// Round 2
// 123.073 us; speedup vs baseline: 1.6406x; 1.6406x over previous
//
#include <hip/hip_runtime.h>
#include <math.h>

// Problem constants (must match reference)
#define NB   2        // images
#define NP   1024     // proposals per image
#define NC   61       // classes incl. background
#define NFG  60       // foreground classes
#define KTOP 100      // detections per image
#define CAP  61440    // worst-case candidates per image (NFG*NP)
#define SELCAP 2048   // top-k collection buffer

__device__ __forceinline__ float clampf(float x, float lo, float hi) {
  return fminf(fmaxf(x, lo), hi);
}

// ---------------------------------------------------------------------------
// Kernel A: per-row softmax stats (max, sum of exp) + zero candidate counters
// one wave (64 lanes) per row of 61 logits
// ---------------------------------------------------------------------------
__global__ void rowstats_kernel(const float* __restrict__ logits,
                                float* __restrict__ rowmax,
                                float* __restrict__ rowsum,
                                int* __restrict__ ccnt) {
  if (blockIdx.x == 0 && threadIdx.x < NB) ccnt[threadIdx.x] = 0;
  int wave = threadIdx.x >> 6, lane = threadIdx.x & 63;
  int row = blockIdx.x * 4 + wave;
  if (row >= NB * NP) return;
  float x = (lane < NC) ? logits[row * NC + lane] : -INFINITY;
  float m = x;
  #pragma unroll
  for (int o = 32; o; o >>= 1) m = fmaxf(m, __shfl_xor(m, o, 64));
  float e = (lane < NC) ? expf(x - m) : 0.0f;
  float s = e;
  #pragma unroll
  for (int o = 32; o; o >>= 1) s += __shfl_xor(s, o, 64);
  if (lane == 0) { rowmax[row] = m; rowsum[row] = s; }
}

// ---------------------------------------------------------------------------
// Kernel B: ONE WAVE per (image, fg class).
//   - ballot-compact valid entries (score > 0.05)
//   - u64-key rank sort (score desc, orig index asc == stable argsort(-key))
//   - greedy NMS: suppression bits live in per-lane registers (bit c of lane t
//     = status of sorted entry c*64+t); per iteration one ballot rebuilds the
//     uniform chunk mask. No barriers, no atomics in the sequential loop.
//   - single atomicAdd per block reserves an output range at the end.
// ---------------------------------------------------------------------------
__global__ void __launch_bounds__(64)
nms_kernel(const float* __restrict__ logits,
           const float* __restrict__ deltas,
           const float* __restrict__ props,
           const float* __restrict__ rowmax,
           const float* __restrict__ rowsum,
           float* __restrict__ cscore,
           int* __restrict__ cflat,
           int* __restrict__ clabel,
           float* __restrict__ cbox,
           int* __restrict__ ccnt) {
  const float SCALE_CLAMP = 4.135166556742356f;  // float(log(1000/16))
  int b = blockIdx.x / NFG;
  int j = blockIdx.x % NFG;
  int cls = j + 1;
  int lane = threadIdx.x;
  unsigned long long lt = (1ull << lane) - 1ull;   // lanes below me

  __shared__ unsigned long long ukey[NP];  // unsorted keys
  __shared__ unsigned long long skey[NP];  // rank-sorted keys
  __shared__ float sbox[NP][4];            // decoded boxes, sorted order

  // 1) threshold + compaction (ballot prefix, no atomics).
  //    key = scorebits<<32 | (1023-n): u64-desc == (score desc, n asc).
  int nv = 0;
  #pragma unroll 4
  for (int c = 0; c < NP / 64; ++c) {
    int n = c * 64 + lane;
    int row = b * NP + n;
    float sc = expf(logits[row * NC + cls] - rowmax[row]) / rowsum[row];
    bool pred = sc > 0.05f;
    unsigned long long m = __ballot(pred);
    if (pred) {
      int pos = nv + __popcll(m & lt);
      ukey[pos] = ((unsigned long long)__float_as_uint(sc) << 32)
                | (unsigned)(NP - 1 - n);
    }
    nv += __popcll(m);
  }
  __syncthreads();
  if (nv == 0) return;
  int chunks = (nv + 63) >> 6;

  // 2) exact rank sort by u64 key descending (keys unique => ranks unique)
  for (int c = 0; c < chunks; ++c) {
    int e = c * 64 + lane;
    if (e < nv) {
      unsigned long long ke = ukey[e];
      int r = 0;
      for (int m2 = 0; m2 < nv; ++m2) r += (ukey[m2] > ke) ? 1 : 0;
      skey[r] = ke;
    }
  }
  __syncthreads();

  // 3) decode + clip boxes for sorted entries
  for (int c = 0; c < chunks; ++c) {
    int p = c * 64 + lane;
    if (p < nv) {
      unsigned long long k = skey[p];
      int n = NP - 1 - (int)(k & 0xFFFFull);
      int row = b * NP + n;
      const float* pr = props + row * 4;
      float w = pr[2] - pr[0], h = pr[3] - pr[1];
      float cx = pr[0] + 0.5f * w, cy = pr[1] + 0.5f * h;
      const float* dd = deltas + (size_t)row * (NC * 4) + cls * 4;
      float dx = dd[0] / 10.0f, dy = dd[1] / 10.0f;
      float dw = fminf(dd[2] / 5.0f, SCALE_CLAMP);
      float dh = fminf(dd[3] / 5.0f, SCALE_CLAMP);
      float pcx = dx * w + cx, pcy = dy * h + cy;
      float pw = expf(dw) * w, ph = expf(dh) * h;
      sbox[p][0] = clampf(pcx - 0.5f * pw, 0.0f, 1024.0f);
      sbox[p][1] = clampf(pcy - 0.5f * ph, 0.0f, 1024.0f);
      sbox[p][2] = clampf(pcx + 0.5f * pw, 0.0f, 1024.0f);
      sbox[p][3] = clampf(pcy + 0.5f * ph, 0.0f, 1024.0f);
    }
  }
  __syncthreads();

  // 4) greedy NMS. supbits/keptbits: bit c of lane t = entry c*64+t.
  unsigned int supbits = 0, keptbits = 0;
  for (int i = 0; i < nv; ++i) {
    int ci = i >> 6, bi = i & 63;
    unsigned long long supmask = __ballot((supbits >> ci) & 1u);
    if ((supmask >> bi) & 1ull) continue;           // uniform skip
    keptbits |= ((lane == bi) ? 1u : 0u) << ci;
    float bx1 = sbox[i][0], by1 = sbox[i][1];       // uniform LDS broadcast
    float bx2 = sbox[i][2], by2 = sbox[i][3];
    float ai = (bx2 - bx1) * (by2 - by1);
    for (int c = 0; c < chunks; ++c) {
      int p = c * 64 + lane;
      float t1 = sbox[p][0], t2 = sbox[p][1];
      float t3 = sbox[p][2], t4 = sbox[p][3];
      float at = (t3 - t1) * (t4 - t2);
      float iw = fmaxf(fminf(bx2, t3) - fmaxf(bx1, t1), 0.0f);
      float ih = fmaxf(fminf(by2, t4) - fmaxf(by1, t2), 0.0f);
      float inter = iw * ih;
      float iou = inter / (ai + at - inter + 1e-9f);
      bool s = (p < nv) && (iou > 0.5f);
      supbits |= (s ? 1u : 0u) << c;
    }
  }

  // 5) reserve output range (ONE atomic per block) and write kept entries
  int total = 0;
  for (int c = 0; c < chunks; ++c)
    total += __popcll(__ballot((keptbits >> c) & 1u));
  int base = 0;
  if (lane == 0) base = atomicAdd(&ccnt[b], total);
  base = __shfl(base, 0);
  int prior = 0;
  for (int c = 0; c < chunks; ++c) {
    unsigned long long mask = __ballot((keptbits >> c) & 1u);
    if ((keptbits >> c) & 1u) {
      int slot = base + prior + __popcll(mask & lt);
      int p = c * 64 + lane;
      int g = b * CAP + slot;
      cscore[g] = __uint_as_float((unsigned)(skey[p] >> 32));
      cflat[g]  = j * NP + p;            // flat index = class*N + sorted pos
      clabel[g] = cls;
      cbox[g * 4 + 0] = sbox[p][0];
      cbox[g * 4 + 1] = sbox[p][1];
      cbox[g * 4 + 2] = sbox[p][2];
      cbox[g * 4 + 3] = sbox[p][3];
    }
    prior += __popcll(mask);
  }
}

// ---------------------------------------------------------------------------
// Kernel C: per-image exact top-100 (score desc, flat-index asc tie-break),
// via histogram threshold + exact rank sort of the surviving ~O(100) set.
// ---------------------------------------------------------------------------
__global__ void __launch_bounds__(256)
topk_kernel(const float* __restrict__ cscore,
            const int* __restrict__ cflat,
            const int* __restrict__ clabel,
            const float* __restrict__ cbox,
            const int* __restrict__ ccnt,
            float* __restrict__ out) {
  int b = blockIdx.x;
  int tid = threadIdx.x;
  int cnt = ccnt[b]; if (cnt > CAP) cnt = CAP;
  const float* cs = cscore + b * CAP;
  const int* cf = cflat + b * CAP;

  __shared__ int hist[256];
  __shared__ int s_thr, s_sel;
  __shared__ float sel_s[SELCAP];
  __shared__ int sel_f[SELCAP];
  __shared__ int sel_i[SELCAP];
  __shared__ int order[KTOP];

  for (int i = tid; i < 256; i += 256) hist[i] = 0;
  __syncthreads();
  for (int i = tid; i < cnt; i += 256) {
    float s = cs[i];
    int bin = (int)(s * 256.0f);
    bin = bin < 0 ? 0 : (bin > 255 ? 255 : bin);
    atomicAdd(&hist[bin], 1);
  }
  __syncthreads();
  if (tid == 0) {
    int acc = 0, t = 255;
    for (; t >= 0; --t) { acc += hist[t]; if (acc >= KTOP) break; }
    s_thr = (acc >= KTOP) ? t : 0;
    s_sel = 0;
  }
  __syncthreads();
  int thr = s_thr;
  for (int i = tid; i < cnt; i += 256) {
    float s = cs[i];
    int bin = (int)(s * 256.0f);
    bin = bin < 0 ? 0 : (bin > 255 ? 255 : bin);
    if (bin >= thr) {
      int p = atomicAdd(&s_sel, 1);
      if (p < SELCAP) { sel_s[p] = s; sel_f[p] = cf[i]; sel_i[p] = i; }
    }
  }
  __syncthreads();
  int nsel = s_sel < SELCAP ? s_sel : SELCAP;

  // exact rank sort of selected set: (score desc, flat idx asc)
  for (int e = tid; e < nsel; e += 256) {
    float ke = sel_s[e]; int fe = sel_f[e];
    int r = 0;
    for (int m = 0; m < nsel; ++m) {
      float km = sel_s[m]; int fm = sel_f[m];
      if (km > ke || (km == ke && fm < fe)) ++r;
    }
    if (r < KTOP) order[r] = e;
  }
  __syncthreads();

  for (int k = tid; k < KTOP; k += 256) {
    float* det = out + (size_t)(b * KTOP + k) * 5;
    float lab;
    if (k < nsel) {
      int e = order[k];
      int ci = sel_i[e];
      const float* bxp = cbox + (size_t)(b * CAP + ci) * 4;
      det[0] = bxp[0]; det[1] = bxp[1]; det[2] = bxp[2]; det[3] = bxp[3];
      det[4] = sel_s[e];
      lab = (float)clabel[b * CAP + ci];
    } else {
      det[0] = det[1] = det[2] = det[3] = 0.0f;
      det[4] = 0.0f;
      lab = 1.0f;  // zero-ties in top_k resolve to class-0 flat slots => label 1
    }
    out[NB * KTOP * 5 + b * KTOP + k] = lab;
  }
}

// ---------------------------------------------------------------------------
extern "C" void kernel_launch(void* const* d_in, const int* in_sizes, int n_in,
                              void* d_out, int out_size, void* d_ws, size_t ws_size,
                              hipStream_t stream) {
  (void)in_sizes; (void)n_in; (void)out_size; (void)ws_size;
  const float* logits = (const float*)d_in[0];   // [B*N, C]
  const float* deltas = (const float*)d_in[1];   // [B*N, C*4]
  const float* props  = (const float*)d_in[2];   // [B, N, 4]
  float* out = (float*)d_out;                    // dets [B,K,5] then labels [B,K]

  // workspace layout (float elements)
  float* wf     = (float*)d_ws;
  float* rowmax = wf;                         // 2048
  float* rowsum = wf + NB * NP;               // 2048
  int*   ccnt   = (int*)(wf + 2 * NB * NP);   // 2 (+2 pad)
  float* cscore = wf + 2 * NB * NP + 4;                       // NB*CAP
  int*   cflat  = (int*)(cscore + (size_t)NB * CAP);          // NB*CAP
  int*   clabel = (int*)(cscore + 2 * (size_t)NB * CAP);      // NB*CAP
  float* cbox   = cscore + 3 * (size_t)NB * CAP;              // NB*CAP*4

  rowstats_kernel<<<(NB * NP) / 4, 256, 0, stream>>>(logits, rowmax, rowsum, ccnt);
  nms_kernel<<<NB * NFG, 64, 0, stream>>>(logits, deltas, props, rowmax, rowsum,
                                          cscore, cflat, clabel, cbox, ccnt);
  topk_kernel<<<NB, 256, 0, stream>>>(cscore, cflat, clabel, cbox, ccnt, out);
}